// Round 5
// baseline (106.869 us; speedup 1.0000x reference)
//
#include <hip/hip_runtime.h>

constexpr int NL = 32;    // layers
constexpr int PPT = 8;    // points per thread -> 8 independent chains (ILP)

// Degree-13 odd polynomial tanh on [-3.4, 3.4], clamped via v_med3.
// No transcendentals (v_exp/v_rcp are ~16 cyc/wave-inst; this is 10 x 2 cyc).
__device__ __forceinline__ float tanh_poly(float x) {
#if __has_builtin(__builtin_amdgcn_fmed3f)
    float t = __builtin_amdgcn_fmed3f(x, -3.4f, 3.4f);
#else
    float t = fminf(fmaxf(x, -3.4f), 3.4f);
#endif
    float s = t * t;
    float u = fmaf(s, 2.3524e-06f, -1.000059e-04f);
    u = fmaf(s, u, 1.7302740e-03f);
    u = fmaf(s, u, -1.5874717e-02f);
    u = fmaf(s, u, 8.5976700e-02f);
    u = fmaf(s, u, -3.0595090e-01f);
    u = fmaf(s, u, 9.9691910e-01f);
    return t * u;
}

// launch_bounds(256, 4): grid is exactly 4 blocks/CU (1024 blocks), so tell
// the allocator 4 waves/SIMD suffice -> up to 128 VGPRs -> the 8 point-chains
// stay live and interleaved instead of serialized (round-4: VGPR=16, 58% busy).
__global__ __launch_bounds__(256, 4) void sympnet_main(
    const float* __restrict__ x,
    const float* __restrict__ act_w,
    const float* __restrict__ bias_b,
    const float* __restrict__ lin_w,
    float* __restrict__ out,
    int nthreads)
{
    // Per-layer folded tables, float4-aligned for ds_read_b128 broadcast.
    // tf[i] = { {m00,m01,m10,m11}, {C0=(M·b).x, C1=(M·b).y, T=aw, 0} }
    // ti[i] = { {m11,-m01,-m10,m00}, {-b0, -b1, -aw, 0} }  (layer 31: P-cols negated)
    __shared__ float4 tf[NL][2];
    __shared__ float4 ti[NL][2];

    int t = threadIdx.x;
    if (t < NL) {
        float m00 = 1.f, m01 = 0.f, m10 = 0.f, m11 = 1.f;
        #pragma unroll
        for (int j = 0; j < 8; ++j) {
            float w = lin_w[t * 8 + j];
            if ((j & 1) == 0) { m00 = fmaf(w, m10, m00); m01 = fmaf(w, m11, m01); }
            else              { m10 = fmaf(w, m00, m10); m11 = fmaf(w, m01, m11); }
        }
        float b0 = bias_b[2 * t], b1 = bias_b[2 * t + 1], aw = act_w[t];
        tf[t][0] = make_float4(m00, m01, m10, m11);
        tf[t][1] = make_float4(fmaf(m00, b0, m01 * b1), fmaf(m10, b0, m11 * b1), aw, 0.f);
        // time-reversal (P -> -P) folded into the FIRST inverse layer (t==31):
        // negate the columns that multiply P.
        float s = (t == NL - 1) ? -1.f : 1.f;
        ti[t][0] = make_float4(m11, s * (-m01), -m10, s * m00);
        ti[t][1] = make_float4(-b0, -b1, -aw, 0.f);
    }
    __syncthreads();

    int gid = blockIdx.x * blockDim.x + t;
    const float2* x2 = (const float2*)x;
    float2* o2 = (float2*)out;

    float Q[PPT], P[PPT];
    #pragma unroll
    for (int k = 0; k < PPT; ++k) {          // strided -> coalesced dwordx2
        float2 v = x2[gid + k * nthreads];
        Q[k] = v.x; P[k] = v.y;
    }

    // ---------------- forward chain (2 layers / iter) ----------------
    #pragma unroll 1
    for (int i = 0; i < NL; i += 2) {
        float4 Fm = tf[i][0],     Fc = tf[i][1];      // even: q += aw*tanh(p)
        float4 Gm = tf[i + 1][0], Gc = tf[i + 1][1];  // odd:  p += aw*tanh(q)
        #pragma unroll
        for (int k = 0; k < PPT; ++k) {
            float Qa = fmaf(Fc.z, tanh_poly(P[k]), Q[k]);
            float Qn = fmaf(Fm.x, Qa, fmaf(Fm.y, P[k], Fc.x));
            float Pn = fmaf(Fm.z, Qa, fmaf(Fm.w, P[k], Fc.y));
            float Pa = fmaf(Gc.z, tanh_poly(Qn), Pn);
            Q[k] = fmaf(Gm.x, Qn, fmaf(Gm.y, Pa, Gc.x));
            P[k] = fmaf(Gm.z, Qn, fmaf(Gm.w, Pa, Gc.y));
        }
    }

    // time reversal is folded into ti[31]; no negation pass needed.

    // ---------------- inverse chain (2 layers / iter) ----------------
    #pragma unroll 1
    for (int i = NL - 1; i > 0; i -= 2) {
        float4 Gm = ti[i][0],     Gc = ti[i][1];      // odd inverse first
        float4 Fm = ti[i - 1][0], Fc = ti[i - 1][1];
        #pragma unroll
        for (int k = 0; k < PPT; ++k) {
            float Qn = fmaf(Gm.x, Q[k], fmaf(Gm.y, P[k], Gc.x));
            float Pn = fmaf(Gm.z, Q[k], fmaf(Gm.w, P[k], Gc.y));
            Pn = fmaf(Gc.z, tanh_poly(Qn), Pn);              // Gc.z = -aw
            float Q2 = fmaf(Fm.x, Qn, fmaf(Fm.y, Pn, Fc.x));
            float P2 = fmaf(Fm.z, Qn, fmaf(Fm.w, Pn, Fc.y));
            Q[k] = fmaf(Fc.z, tanh_poly(P2), Q2);            // Fc.z = -aw
            P[k] = P2;
        }
    }

    // final scale [1, -1]
    #pragma unroll
    for (int k = 0; k < PPT; ++k) {
        float2 o; o.x = Q[k]; o.y = -P[k];
        o2[gid + k * nthreads] = o;
    }
}

extern "C" void kernel_launch(void* const* d_in, const int* in_sizes, int n_in,
                              void* d_out, int out_size, void* d_ws, size_t ws_size,
                              hipStream_t stream) {
    const float* x      = (const float*)d_in[0];
    const float* act_w  = (const float*)d_in[1];
    const float* bias_b = (const float*)d_in[2];
    const float* lin_w  = (const float*)d_in[3];
    float* out = (float*)d_out;

    int npts = in_sizes[0] / 2;            // 2097152
    int nthreads = npts / PPT;             // 262144
    int blocks = nthreads / 256;           // 1024 = exactly 4 blocks/CU
    sympnet_main<<<blocks, 256, 0, stream>>>(x, act_w, bias_b, lin_w, out, nthreads);
}